// Round 3
// baseline (615.118 us; speedup 1.0000x reference)
//
#include <hip/hip_runtime.h>
#include <cstdint>
#include <cstddef>

#define B_ 64
#define S_ 2048
#define H_ 512
#define R_ 256
#define M_ (B_ * S_)   // 131072
#define NEGV (-1.0e9f)

typedef short short8 __attribute__((ext_vector_type(8)));
typedef unsigned short u16x8 __attribute__((ext_vector_type(8)));
typedef float f32x4 __attribute__((ext_vector_type(4)));
typedef unsigned short u16;

// ---------- helpers ----------
__device__ __forceinline__ u16 f2b(float x) {
    union { float f; uint32_t u; } c; c.f = x;
    uint32_t u = c.u;
    uint32_t r = (u + 0x7fffu + ((u >> 16) & 1u)) >> 16;   // RNE
    return (u16)r;
}
__device__ __forceinline__ float b2f(u16 u) {
    union { uint32_t u; float f; } c; c.u = ((uint32_t)u) << 16;
    return c.f;
}
__device__ __forceinline__ void load_lds16(const void* g, void* l) {
    __builtin_amdgcn_global_load_lds((__attribute__((address_space(1))) void*)g,
                                     (__attribute__((address_space(3))) void*)l,
                                     16, 0, 0);
}

// ---------- K0: convert sent_h to bf16 ----------
__global__ void k_convert(const float* __restrict__ sent, u16* __restrict__ sentb) {
    const long tstride = 1048576;   // 4096 blocks * 256 threads
    long i0 = (long)blockIdx.x * 256 + threadIdx.x;
    #pragma unroll
    for (int u = 0; u < 8; ++u) {
        long i = i0 + (long)u * tstride;
        float4 v0 = ((const float4*)sent)[2 * i];
        float4 v1 = ((const float4*)sent)[2 * i + 1];
        u16x8 o;
        o[0] = f2b(v0.x); o[1] = f2b(v0.y); o[2] = f2b(v0.z); o[3] = f2b(v0.w);
        o[4] = f2b(v1.x); o[5] = f2b(v1.y); o[6] = f2b(v1.z); o[7] = f2b(v1.w);
        ((u16x8*)sentb)[i] = o;
    }
}

// ---------- K1: base[b,k] = rel@Wr^T + Wr_b + pool@Wg^T + Wg_b + Wh_b  (+ Wh_w f32->bf16) ----------
__global__ void k_base(const float* __restrict__ rel, const float* __restrict__ pool,
                       const float* __restrict__ Wg_w, const float* __restrict__ Wg_b,
                       const float* __restrict__ Wh_b,
                       const float* __restrict__ Wr_w, const float* __restrict__ Wr_b,
                       const float* __restrict__ whw, float* __restrict__ base,
                       u16* __restrict__ whwb) {
    int tid = threadIdx.x;
    {   // convert Wh_w: 262144 elems = 65536 float4 groups; exactly one per thread
        int gi = blockIdx.x * 256 + tid;
        float4 v = ((const float4*)whw)[gi];
        ushort4 o; o.x = f2b(v.x); o.y = f2b(v.y); o.z = f2b(v.z); o.w = f2b(v.w);
        ((ushort4*)whwb)[gi] = o;
    }
    int b = blockIdx.x >> 2, q = blockIdx.x & 3;
    __shared__ __attribute__((aligned(16))) float srel[R_];
    __shared__ __attribute__((aligned(16))) float spool[H_];
    __shared__ float accs[128];
    srel[tid & 255] = rel[b * R_ + (tid & 255)];
    for (int i = tid; i < H_; i += 256) spool[i] = pool[b * H_ + i];
    __syncthreads();
    int kk = tid & 127, half = tid >> 7;
    int k = q * 128 + kk;
    float acc = 0.f;
    if (half == 0) {
        acc = Wr_b[k] + Wg_b[k] + Wh_b[k];
        const float4* wr = (const float4*)(Wr_w + (size_t)k * R_);
        #pragma unroll 8
        for (int r4 = 0; r4 < R_ / 4; ++r4) {
            float4 w = wr[r4]; float4 x = ((const float4*)srel)[r4];
            acc += w.x * x.x + w.y * x.y + w.z * x.z + w.w * x.w;
        }
        const float4* wg = (const float4*)(Wg_w + (size_t)k * H_);
        #pragma unroll 8
        for (int h4 = 0; h4 < 32; ++h4) {
            float4 w = wg[h4]; float4 x = ((const float4*)spool)[h4];
            acc += w.x * x.x + w.y * x.y + w.z * x.z + w.w * x.w;
        }
    } else {
        const float4* wg = (const float4*)(Wg_w + (size_t)k * H_);
        #pragma unroll 8
        for (int h4 = 32; h4 < 128; ++h4) {
            float4 w = wg[h4]; float4 x = ((const float4*)spool)[h4];
            acc += w.x * x.x + w.y * x.y + w.z * x.z + w.w * x.w;
        }
    }
    if (half) accs[kk] = acc;
    __syncthreads();
    if (!half) base[b * H_ + k] = acc + accs[kk];
}

// ---------- K2: main GEMM [M,512]x[512,512]^T + tanh/alpha epilogue -> partial[4][M] ----------
// v3: B (Wh_w, 512 KB, L2/L3-resident, shared by all blocks) is loaded straight from
// global into registers each K-step -- no LDS staging for B. LDS drops 66.5 -> ~33.5 KB
// => 4 blocks/CU (16 waves/CU, was 2 blocks/8 waves), and the per-step barrier drains
// only A's 16 KB prefetch. A keeps the global_load_lds double-buffered pipeline.
// __launch_bounds__(256,4) pins VGPR <= 128 so occupancy stays LDS-limited at 4 blocks.
__launch_bounds__(256, 4)
__global__ void k_gemm(const u16* __restrict__ A,    // [M, 512] bf16
                       const u16* __restrict__ Bw,   // [512, 512] bf16 (Wh_w, B^T layout)
                       const float* __restrict__ base,  // [B_, H_]
                       const float* __restrict__ alpha, // [H_]
                       float* __restrict__ partial)     // [4][M]
{
    const int K = 512;
    int j = blockIdx.x;
    int xcd  = j & 7;
    int slot = j >> 3;
    int nb   = slot & 3;
    int mb   = (slot >> 2) * 8 + xcd;   // 0..1023, bijective over grid 4096
    int m0 = mb * 128;
    int n0 = nb * 128;
    int b  = m0 >> 11;   // m0 / S_

    int tid = threadIdx.x;
    int w  = tid >> 6;      // wave 0..3
    int l  = tid & 63;
    int wm = w & 1, wn = w >> 1;
    int lr = l & 15;        // C col / frag row
    int lq = l >> 4;        // quad

    __shared__ __attribute__((aligned(16))) u16 smA[2][128 * 64];   // 2 x 16 KB
    __shared__ float red[2][2][64];

    f32x4 zero = {0.f, 0.f, 0.f, 0.f};
    f32x4 acc[4][4];
    #pragma unroll
    for (int i = 0; i < 4; ++i)
        #pragma unroll
        for (int jj = 0; jj < 4; ++jj) acc[i][jj] = zero;

    // per-lane B fragment base pointers: row = n0 + wn*64 + ni*16 + lr, col = lq*8
    // (exactly the element mapping the old LDS round-trip delivered)
    const u16* bp[4];
    #pragma unroll
    for (int ni = 0; ni < 4; ++ni)
        bp[ni] = Bw + (size_t)(n0 + wn * 64 + ni * 16 + lr) * K + lq * 8;

    // stage one 128x64 K-slab of A into buffer `buf`
    auto STAGE = [&](int buf, int kt) {
        int k0 = kt * 64;
        #pragma unroll
        for (int i = 0; i < 4; ++i) {
            int c  = w * 4 + i;
            int mf = c >> 1, kc = c & 1;
            int row = mf * 16 + lr;
            int col = k0 + kc * 32 + lq * 8;
            const u16* ga = A + (size_t)(m0 + row) * K + col;
            load_lds16(ga, smA[buf] + c * 512);
        }
    };

    STAGE(0, 0);
    __syncthreads();

    #pragma unroll
    for (int kt = 0; kt < 8; ++kt) {
        int cur = kt & 1;
        // B fragments for this step, straight from L2 (issued first: oldest in queue,
        // latency overlaps the A ds_reads below)
        short8 bf[2][4];
        #pragma unroll
        for (int kc = 0; kc < 2; ++kc)
            #pragma unroll
            for (int ni = 0; ni < 4; ++ni)
                bf[kc][ni] = *(const short8*)(bp[ni] + kt * 64 + kc * 32);
        if (kt < 7) STAGE(cur ^ 1, kt + 1);   // prefetch next A slab; flies under compute
        __builtin_amdgcn_s_setprio(1);
        #pragma unroll
        for (int kc = 0; kc < 2; ++kc) {
            short8 af[4];
            #pragma unroll
            for (int mi = 0; mi < 4; ++mi)
                af[mi] = *(const short8*)(smA[cur] + ((wm * 4 + mi) * 2 + kc) * 512 + l * 8);
            #pragma unroll
            for (int mi = 0; mi < 4; ++mi)
                #pragma unroll
                for (int ni = 0; ni < 4; ++ni)
                    acc[mi][ni] = __builtin_amdgcn_mfma_f32_16x16x32_bf16(af[mi], bf[kc][ni], acc[mi][ni], 0, 0, 0);
        }
        __builtin_amdgcn_s_setprio(0);
        __syncthreads();
    }

    // epilogue: sum_n tanh(acc + base[b,n]) * alpha[n] = sum(a) - sum 2a/(exp2(C2*v)+1)
    const float C2 = 2.8853900817779268f;   // 2*log2(e)
    float base2[4], a2[4];
    float asum = 0.f;
    #pragma unroll
    for (int ni = 0; ni < 4; ++ni) {
        int n = n0 + wn * 64 + ni * 16 + lr;
        base2[ni] = C2 * base[b * H_ + n];
        float al  = alpha[n];
        a2[ni] = 2.0f * al;
        asum  += al;
    }
    #pragma unroll
    for (int mi = 0; mi < 4; ++mi) {
        #pragma unroll
        for (int r = 0; r < 4; ++r) {
            float s = asum;
            #pragma unroll
            for (int ni = 0; ni < 4; ++ni) {
                float f  = fmaf(acc[mi][ni][r], C2, base2[ni]);
                float e  = __builtin_amdgcn_exp2f(f);
                float rr = __builtin_amdgcn_rcpf(e + 1.0f);
                s = fmaf(-a2[ni], rr, s);
            }
            s += __shfl_xor(s, 1);
            s += __shfl_xor(s, 2);
            s += __shfl_xor(s, 4);
            s += __shfl_xor(s, 8);
            if (lr == 0) red[wm][wn][mi * 16 + lq * 4 + r] = s;
        }
    }
    __syncthreads();
    if (tid < 128) {
        int wmi = tid >> 6, row = tid & 63;
        float sum = red[wmi][0][row] + red[wmi][1][row];
        partial[(size_t)nb * M_ + m0 + wmi * 64 + row] = sum;
    }
}

// ---------- K3: softmax over S per b ----------
__global__ void k_softmax(const float* __restrict__ partial, const int* __restrict__ mask,
                          const float* __restrict__ alpha_b, float* __restrict__ wout) {
    int b = blockIdx.x;
    int tid = threadIdx.x;
    __shared__ float sred[8];
    float x[8];
    float ab = alpha_b[0];
    float lmax = -3.0e38f;
    #pragma unroll
    for (int jj = 0; jj < 8; ++jj) {
        int s = tid + jj * 256;
        size_t m = (size_t)b * S_ + s;
        float v = partial[m] + partial[(size_t)M_ + m] + partial[2 * (size_t)M_ + m] + partial[3 * (size_t)M_ + m] + ab;
        if (mask[b * S_ + s] == 0) v = NEGV;
        x[jj] = v;
        lmax = fmaxf(lmax, v);
    }
    #pragma unroll
    for (int off = 1; off < 64; off <<= 1) lmax = fmaxf(lmax, __shfl_xor(lmax, off));
    int wv = tid >> 6, l = tid & 63;
    if (l == 0) sred[wv] = lmax;
    __syncthreads();
    float gmax = fmaxf(fmaxf(sred[0], sred[1]), fmaxf(sred[2], sred[3]));
    float lsum = 0.f;
    #pragma unroll
    for (int jj = 0; jj < 8; ++jj) { x[jj] = __expf(x[jj] - gmax); lsum += x[jj]; }
    #pragma unroll
    for (int off = 1; off < 64; off <<= 1) lsum += __shfl_xor(lsum, off);
    if (l == 0) sred[4 + wv] = lsum;
    __syncthreads();
    float inv = 1.f / (sred[4] + sred[5] + sred[6] + sred[7]);
    #pragma unroll
    for (int jj = 0; jj < 8; ++jj) {
        int s = tid + jj * 256;
        wout[(size_t)b * S_ + s] = x[jj] * inv;
    }
}

// ---------- K4: t[b,h'] = sum_s w[b,s] * sent_h_bf16[b,s,h'] ----------
__global__ void k_wsum(const u16* __restrict__ sentb, const float* __restrict__ wrow_g,
                       float* __restrict__ t) {
    int b  = blockIdx.x >> 3;
    int hc = blockIdx.x & 7;
    int tid = threadIdx.x;
    __shared__ __attribute__((aligned(16))) float wrow[S_];   // 8 KB
    __shared__ float red[64][33];                             // 8.4 KB, padded
    ((float4*)wrow)[tid]       = ((const float4*)(wrow_g + (size_t)b * S_))[tid];
    ((float4*)wrow)[tid + 256] = ((const float4*)(wrow_g + (size_t)b * S_))[tid + 256];
    __syncthreads();
    int hi = tid & 7;          // 8 col-groups x 8 cols = 64 cols
    int sg = tid >> 3;         // 32 s-groups
    const u16* bp = sentb + (size_t)b * S_ * H_ + hc * 64 + hi * 8;
    float acc[8] = {0.f, 0.f, 0.f, 0.f, 0.f, 0.f, 0.f, 0.f};
    #pragma unroll 2
    for (int sb = 0; sb < S_; sb += 256) {
        u16x8 v[8];
        #pragma unroll
        for (int u = 0; u < 8; ++u)
            v[u] = *(const u16x8*)(bp + (size_t)(sb + sg + u * 32) * H_);
        #pragma unroll
        for (int u = 0; u < 8; ++u) {
            float wgt = wrow[sb + sg + u * 32];
            #pragma unroll
            for (int e = 0; e < 8; ++e)
                acc[e] = fmaf(wgt, b2f((u16)v[u][e]), acc[e]);
        }
    }
    #pragma unroll
    for (int e = 0; e < 8; ++e) red[hi * 8 + e][sg] = acc[e];
    __syncthreads();
    if (tid < 64) {
        float s = 0.f;
        #pragma unroll
        for (int g = 0; g < 32; ++g) s += red[tid][g];
        t[(size_t)b * H_ + hc * 64 + tid] = s;
    }
}

// ---------- K5: att_res[b,h] = Wh_b[h] + sum_h' t[b,h'] * Wh_w[h,h']  (grid 256) ----------
__global__ void k_att(const float* __restrict__ t, const float* __restrict__ Whw,
                      const float* __restrict__ Whb, float* __restrict__ out) {
    int tid = threadIdx.x;
    int b = blockIdx.x >> 2, q = blockIdx.x & 3;
    __shared__ __attribute__((aligned(16))) float st[H_];
    __shared__ float accs[128];
    for (int i = tid; i < H_; i += 256) st[i] = t[(size_t)b * H_ + i];
    __syncthreads();
    int hh = tid & 127, half = tid >> 7;
    int h = q * 128 + hh;
    const float4* wr = (const float4*)(Whw + (size_t)h * H_) + half * 64;
    const float4* sx = (const float4*)st + half * 64;
    float acc = 0.f;
    #pragma unroll 8
    for (int i = 0; i < 64; ++i) {
        float4 w = wr[i]; float4 x = sx[i];
        acc += w.x * x.x + w.y * x.y + w.z * x.z + w.w * x.w;
    }
    if (half) accs[hh] = acc;
    __syncthreads();
    if (!half) out[(size_t)b * H_ + h] = acc + accs[hh] + Whb[h];
}

extern "C" void kernel_launch(void* const* d_in, const int* in_sizes, int n_in,
                              void* d_out, int out_size, void* d_ws, size_t ws_size,
                              hipStream_t stream) {
    const float* sent_h  = (const float*)d_in[0];
    const float* rel     = (const float*)d_in[1];
    const float* pool    = (const float*)d_in[2];
    const int*   mask    = (const int*)d_in[3];
    const float* Wg_w    = (const float*)d_in[4];
    const float* Wg_b    = (const float*)d_in[5];
    const float* Wh_w    = (const float*)d_in[6];
    const float* Wh_b    = (const float*)d_in[7];
    const float* Wr_w    = (const float*)d_in[8];
    const float* Wr_b    = (const float*)d_in[9];
    const float* alpha_w = (const float*)d_in[10];
    const float* alpha_b = (const float*)d_in[11];
    float* out = (float*)d_out;

    char* ws = (char*)d_ws;
    u16*   sentb   = (u16*)ws;                                   // 134217728 B
    u16*   whwb    = (u16*)(ws + 134217728);                     // 524288 B
    float* base    = (float*)(ws + 134217728 + 524288);          // 131072 B
    float* partial = (float*)(ws + 134217728 + 524288 + 131072); // 2097152 B
    float* tbuf    = (float*)(ws + 134217728 + 524288 + 131072 + 2097152); // 131072 B

    float* att_out = out;             // [64,512]
    float* w_out   = out + B_ * H_;   // [64,2048]

    k_convert<<<dim3(4096), dim3(256), 0, stream>>>(sent_h, sentb);
    k_base<<<dim3(256), dim3(256), 0, stream>>>(rel, pool, Wg_w, Wg_b, Wh_b, Wr_w, Wr_b, Wh_w, base, whwb);
    k_gemm<<<dim3((M_ / 128) * 4), dim3(256), 0, stream>>>(sentb, whwb, base, alpha_w, partial);
    k_softmax<<<dim3(B_), dim3(256), 0, stream>>>(partial, mask, alpha_b, w_out);
    k_wsum<<<dim3(B_ * 8), dim3(256), 0, stream>>>(sentb, w_out, tbuf);
    k_att<<<dim3(256), dim3(256), 0, stream>>>(tbuf, Wh_w, Wh_b, att_out);
}

// Round 4
// 578.560 us; speedup vs baseline: 1.0632x; 1.0632x over previous
//
#include <hip/hip_runtime.h>
#include <cstdint>
#include <cstddef>

#define B_ 64
#define S_ 2048
#define H_ 512
#define R_ 256
#define M_ (B_ * S_)   // 131072
#define NEGV (-1.0e9f)

typedef short short8 __attribute__((ext_vector_type(8)));
typedef unsigned short u16x8 __attribute__((ext_vector_type(8)));
typedef float f32x4 __attribute__((ext_vector_type(4)));
typedef unsigned short u16;

// ---------- helpers ----------
__device__ __forceinline__ u16 f2b(float x) {
    union { float f; uint32_t u; } c; c.f = x;
    uint32_t u = c.u;
    uint32_t r = (u + 0x7fffu + ((u >> 16) & 1u)) >> 16;   // RNE
    return (u16)r;
}
__device__ __forceinline__ float b2f(u16 u) {
    union { uint32_t u; float f; } c; c.u = ((uint32_t)u) << 16;
    return c.f;
}
// HW packed f32->bf16 (RNE, identical result to f2b): dst.lo=cvt(lo), dst.hi=cvt(hi)
__device__ __forceinline__ uint32_t pk2(float lo, float hi) {
    uint32_t r;
    asm("v_cvt_pk_bf16_f32 %0, %1, %2" : "=v"(r) : "v"(lo), "v"(hi));
    return r;
}
__device__ __forceinline__ void load_lds16(const void* g, void* l) {
    __builtin_amdgcn_global_load_lds((__attribute__((address_space(1))) void*)g,
                                     (__attribute__((address_space(3))) void*)l,
                                     16, 0, 0);
}

// ---------- K1: base[b,k] = rel@Wr^T + Wr_b + pool@Wg^T + Wg_b + Wh_b  (+ Wh_w f32->bf16) ----------
__global__ void k_base(const float* __restrict__ rel, const float* __restrict__ pool,
                       const float* __restrict__ Wg_w, const float* __restrict__ Wg_b,
                       const float* __restrict__ Wh_b,
                       const float* __restrict__ Wr_w, const float* __restrict__ Wr_b,
                       const float* __restrict__ whw, float* __restrict__ base,
                       u16* __restrict__ whwb) {
    int tid = threadIdx.x;
    {   // convert Wh_w: 262144 elems = 65536 float4 groups; exactly one per thread
        int gi = blockIdx.x * 256 + tid;
        float4 v = ((const float4*)whw)[gi];
        ushort4 o; o.x = f2b(v.x); o.y = f2b(v.y); o.z = f2b(v.z); o.w = f2b(v.w);
        ((ushort4*)whwb)[gi] = o;
    }
    int b = blockIdx.x >> 2, q = blockIdx.x & 3;
    __shared__ __attribute__((aligned(16))) float srel[R_];
    __shared__ __attribute__((aligned(16))) float spool[H_];
    __shared__ float accs[128];
    srel[tid & 255] = rel[b * R_ + (tid & 255)];
    for (int i = tid; i < H_; i += 256) spool[i] = pool[b * H_ + i];
    __syncthreads();
    int kk = tid & 127, half = tid >> 7;
    int k = q * 128 + kk;
    float acc = 0.f;
    if (half == 0) {
        acc = Wr_b[k] + Wg_b[k] + Wh_b[k];
        const float4* wr = (const float4*)(Wr_w + (size_t)k * R_);
        #pragma unroll 8
        for (int r4 = 0; r4 < R_ / 4; ++r4) {
            float4 w = wr[r4]; float4 x = ((const float4*)srel)[r4];
            acc += w.x * x.x + w.y * x.y + w.z * x.z + w.w * x.w;
        }
        const float4* wg = (const float4*)(Wg_w + (size_t)k * H_);
        #pragma unroll 8
        for (int h4 = 0; h4 < 32; ++h4) {
            float4 w = wg[h4]; float4 x = ((const float4*)spool)[h4];
            acc += w.x * x.x + w.y * x.y + w.z * x.z + w.w * x.w;
        }
    } else {
        const float4* wg = (const float4*)(Wg_w + (size_t)k * H_);
        #pragma unroll 8
        for (int h4 = 32; h4 < 128; ++h4) {
            float4 w = wg[h4]; float4 x = ((const float4*)spool)[h4];
            acc += w.x * x.x + w.y * x.y + w.z * x.z + w.w * x.w;
        }
    }
    if (half) accs[kk] = acc;
    __syncthreads();
    if (!half) base[b * H_ + k] = acc + accs[kk];
}

// ---------- K2: main GEMM [M,512]x[512,512]^T + tanh/alpha epilogue -> partial[4][M] ----------
// v4: k_convert is FUSED into A-staging. A (sent_h, f32) is reg-staged: 8x global_load_dwordx4
// issued early each step, converted with v_cvt_pk_bf16_f32 after the MFMA phase, ds_write_b128
// into the next LDS buffer (layout byte-identical to the old global_load_lds path, so fragment
// reads are untouched). B reverts to the round-2 global_load_lds double-buffer (prefetched a
// full step ahead -> its latency stays off the critical path; round-3 showed B-in-regs puts an
// L2 round-trip on the critical path every step).
__launch_bounds__(256)
__global__ void k_gemm(const float* __restrict__ A32,  // [M, 512] f32 (sent_h)
                       const u16* __restrict__ Bw,     // [512, 512] bf16 (Wh_w, B^T layout)
                       const float* __restrict__ base,  // [B_, H_]
                       const float* __restrict__ alpha, // [H_]
                       float* __restrict__ partial)     // [4][M]
{
    const int K = 512;
    int j = blockIdx.x;
    int xcd  = j & 7;
    int slot = j >> 3;
    int nb   = slot & 3;
    int mb   = (slot >> 2) * 8 + xcd;   // 0..1023, bijective over grid 4096
    int m0 = mb * 128;
    int n0 = nb * 128;
    int b  = m0 >> 11;   // m0 / S_

    int tid = threadIdx.x;
    int w  = tid >> 6;      // wave 0..3
    int l  = tid & 63;
    int wm = w & 1, wn = w >> 1;
    int lr = l & 15;        // C col / frag row
    int lq = l >> 4;        // quad

    __shared__ __attribute__((aligned(16))) u16 smA[2][128 * 64];   // 2 x 16 KB
    __shared__ __attribute__((aligned(16))) u16 smB[2][128 * 64];   // 2 x 16 KB
    __shared__ float red[2][2][64];

    f32x4 zero = {0.f, 0.f, 0.f, 0.f};
    f32x4 acc[4][4];
    #pragma unroll
    for (int i = 0; i < 4; ++i)
        #pragma unroll
        for (int jj = 0; jj < 4; ++jj) acc[i][jj] = zero;

    // per-chunk A geometry (chunk c = w*4+i): row = (c>>1)*16+lr, colgroup = (c&1)*32+lq*8
    int arow[4], acolg[4];
    #pragma unroll
    for (int i = 0; i < 4; ++i) {
        int c = w * 4 + i;
        arow[i]  = (c >> 1) * 16 + lr;
        acolg[i] = (c & 1) * 32 + lq * 8;
    }

    float4 av[4][2];   // in-flight A f32 (32 VGPR)

    // issue 8 f32 global loads for K-slab kt
    auto LOAD_A = [&](int kt) {
        int k0 = kt * 64;
        #pragma unroll
        for (int i = 0; i < 4; ++i) {
            const float4* ga = (const float4*)(A32 + (size_t)(m0 + arow[i]) * K + k0 + acolg[i]);
            av[i][0] = ga[0];
            av[i][1] = ga[1];
        }
    };
    // convert + deposit into LDS buffer `buf` (same layout as global_load_lds produced)
    auto WRITE_A = [&](int buf) {
        #pragma unroll
        for (int i = 0; i < 4; ++i) {
            uint4 pv;
            pv.x = pk2(av[i][0].x, av[i][0].y);
            pv.y = pk2(av[i][0].z, av[i][0].w);
            pv.z = pk2(av[i][1].x, av[i][1].y);
            pv.w = pk2(av[i][1].z, av[i][1].w);
            *(uint4*)(smA[buf] + (w * 4 + i) * 512 + l * 8) = pv;
        }
    };
    // B: global_load_lds staging, unchanged from round 2
    auto STAGE_B = [&](int buf, int kt) {
        int k0 = kt * 64;
        #pragma unroll
        for (int i = 0; i < 4; ++i) {
            int c  = w * 4 + i;
            int mf = c >> 1, kc = c & 1;
            int row = mf * 16 + lr;
            int col = k0 + kc * 32 + lq * 8;
            const u16* gb = Bw + (size_t)(n0 + row) * K + col;
            load_lds16(gb, smB[buf] + c * 512);
        }
    };

    LOAD_A(0);         // oldest in vm queue
    STAGE_B(0, 0);
    WRITE_A(0);        // compiler waits vmcnt(4): A regs ready, B still in flight
    __syncthreads();   // drains B (vmcnt 0) + lgkm

    #pragma unroll
    for (int kt = 0; kt < 8; ++kt) {
        int cur = kt & 1;
        if (kt < 7) {
            LOAD_A(kt + 1);            // f32 A into regs (oldest)
            STAGE_B(cur ^ 1, kt + 1);  // B straight to LDS
        }
        __builtin_amdgcn_s_setprio(1);
        #pragma unroll
        for (int kc = 0; kc < 2; ++kc) {
            short8 af[4], bf[4];
            #pragma unroll
            for (int mi = 0; mi < 4; ++mi)
                af[mi] = *(const short8*)(smA[cur] + ((wm * 4 + mi) * 2 + kc) * 512 + l * 8);
            #pragma unroll
            for (int ni = 0; ni < 4; ++ni)
                bf[ni] = *(const short8*)(smB[cur] + ((wn * 4 + ni) * 2 + kc) * 512 + l * 8);
            #pragma unroll
            for (int mi = 0; mi < 4; ++mi)
                #pragma unroll
                for (int ni = 0; ni < 4; ++ni)
                    acc[mi][ni] = __builtin_amdgcn_mfma_f32_16x16x32_bf16(af[mi], bf[ni], acc[mi][ni], 0, 0, 0);
        }
        __builtin_amdgcn_s_setprio(0);
        if (kt < 7) WRITE_A(cur ^ 1);  // A loads had the whole MFMA phase to land
        __syncthreads();
    }

    // epilogue: sum_n tanh(acc + base[b,n]) * alpha[n] = sum(a) - sum 2a/(exp2(C2*v)+1)
    const float C2 = 2.8853900817779268f;   // 2*log2(e)
    float base2[4], a2[4];
    float asum = 0.f;
    #pragma unroll
    for (int ni = 0; ni < 4; ++ni) {
        int n = n0 + wn * 64 + ni * 16 + lr;
        base2[ni] = C2 * base[b * H_ + n];
        float al  = alpha[n];
        a2[ni] = 2.0f * al;
        asum  += al;
    }
    #pragma unroll
    for (int mi = 0; mi < 4; ++mi) {
        #pragma unroll
        for (int r = 0; r < 4; ++r) {
            float s = asum;
            #pragma unroll
            for (int ni = 0; ni < 4; ++ni) {
                float f  = fmaf(acc[mi][ni][r], C2, base2[ni]);
                float e  = __builtin_amdgcn_exp2f(f);
                float rr = __builtin_amdgcn_rcpf(e + 1.0f);
                s = fmaf(-a2[ni], rr, s);
            }
            s += __shfl_xor(s, 1);
            s += __shfl_xor(s, 2);
            s += __shfl_xor(s, 4);
            s += __shfl_xor(s, 8);
            if (lr == 0) red[wm][wn][mi * 16 + lq * 4 + r] = s;
        }
    }
    __syncthreads();
    if (tid < 128) {
        int wmi = tid >> 6, row = tid & 63;
        float sum = red[wmi][0][row] + red[wmi][1][row];
        partial[(size_t)nb * M_ + m0 + wmi * 64 + row] = sum;
    }
}

// ---------- K3: softmax over S per b ----------
__global__ void k_softmax(const float* __restrict__ partial, const int* __restrict__ mask,
                          const float* __restrict__ alpha_b, float* __restrict__ wout) {
    int b = blockIdx.x;
    int tid = threadIdx.x;
    __shared__ float sred[8];
    float x[8];
    float ab = alpha_b[0];
    float lmax = -3.0e38f;
    #pragma unroll
    for (int jj = 0; jj < 8; ++jj) {
        int s = tid + jj * 256;
        size_t m = (size_t)b * S_ + s;
        float v = partial[m] + partial[(size_t)M_ + m] + partial[2 * (size_t)M_ + m] + partial[3 * (size_t)M_ + m] + ab;
        if (mask[b * S_ + s] == 0) v = NEGV;
        x[jj] = v;
        lmax = fmaxf(lmax, v);
    }
    #pragma unroll
    for (int off = 1; off < 64; off <<= 1) lmax = fmaxf(lmax, __shfl_xor(lmax, off));
    int wv = tid >> 6, l = tid & 63;
    if (l == 0) sred[wv] = lmax;
    __syncthreads();
    float gmax = fmaxf(fmaxf(sred[0], sred[1]), fmaxf(sred[2], sred[3]));
    float lsum = 0.f;
    #pragma unroll
    for (int jj = 0; jj < 8; ++jj) { x[jj] = __expf(x[jj] - gmax); lsum += x[jj]; }
    #pragma unroll
    for (int off = 1; off < 64; off <<= 1) lsum += __shfl_xor(lsum, off);
    if (l == 0) sred[4 + wv] = lsum;
    __syncthreads();
    float inv = 1.f / (sred[4] + sred[5] + sred[6] + sred[7]);
    #pragma unroll
    for (int jj = 0; jj < 8; ++jj) {
        int s = tid + jj * 256;
        wout[(size_t)b * S_ + s] = x[jj] * inv;
    }
}

// ---------- K4: t[b,h'] = sum_s w[b,s] * sent_h[b,s,h']  (f32 source, no sentb needed) ----------
__global__ void k_wsum(const float* __restrict__ sent, const float* __restrict__ wrow_g,
                       float* __restrict__ t) {
    int b  = blockIdx.x >> 3;
    int hc = blockIdx.x & 7;
    int tid = threadIdx.x;
    __shared__ __attribute__((aligned(16))) float wrow[S_];   // 8 KB
    __shared__ float red[64][33];                             // 8.4 KB, padded
    ((float4*)wrow)[tid]       = ((const float4*)(wrow_g + (size_t)b * S_))[tid];
    ((float4*)wrow)[tid + 256] = ((const float4*)(wrow_g + (size_t)b * S_))[tid + 256];
    __syncthreads();
    int hi = tid & 7;          // 8 col-groups x 8 cols = 64 cols
    int sg = tid >> 3;         // 32 s-groups
    const float* bp = sent + (size_t)b * S_ * H_ + hc * 64 + hi * 8;
    float acc[8] = {0.f, 0.f, 0.f, 0.f, 0.f, 0.f, 0.f, 0.f};
    for (int sb = 0; sb < S_; sb += 256) {
        float4 v[8][2];
        #pragma unroll
        for (int u = 0; u < 8; ++u) {
            const float4* p = (const float4*)(bp + (size_t)(sb + sg + u * 32) * H_);
            v[u][0] = p[0]; v[u][1] = p[1];
        }
        #pragma unroll
        for (int u = 0; u < 8; ++u) {
            float wgt = wrow[sb + sg + u * 32];
            acc[0] = fmaf(wgt, v[u][0].x, acc[0]);
            acc[1] = fmaf(wgt, v[u][0].y, acc[1]);
            acc[2] = fmaf(wgt, v[u][0].z, acc[2]);
            acc[3] = fmaf(wgt, v[u][0].w, acc[3]);
            acc[4] = fmaf(wgt, v[u][1].x, acc[4]);
            acc[5] = fmaf(wgt, v[u][1].y, acc[5]);
            acc[6] = fmaf(wgt, v[u][1].z, acc[6]);
            acc[7] = fmaf(wgt, v[u][1].w, acc[7]);
        }
    }
    #pragma unroll
    for (int e = 0; e < 8; ++e) red[hi * 8 + e][sg] = acc[e];
    __syncthreads();
    if (tid < 64) {
        float s = 0.f;
        #pragma unroll
        for (int g = 0; g < 32; ++g) s += red[tid][g];
        t[(size_t)b * H_ + hc * 64 + tid] = s;
    }
}

// ---------- K5: att_res[b,h] = Wh_b[h] + sum_h' t[b,h'] * Wh_w[h,h']  (grid 256) ----------
__global__ void k_att(const float* __restrict__ t, const float* __restrict__ Whw,
                      const float* __restrict__ Whb, float* __restrict__ out) {
    int tid = threadIdx.x;
    int b = blockIdx.x >> 2, q = blockIdx.x & 3;
    __shared__ __attribute__((aligned(16))) float st[H_];
    __shared__ float accs[128];
    for (int i = tid; i < H_; i += 256) st[i] = t[(size_t)b * H_ + i];
    __syncthreads();
    int hh = tid & 127, half = tid >> 7;
    int h = q * 128 + hh;
    const float4* wr = (const float4*)(Whw + (size_t)h * H_) + half * 64;
    const float4* sx = (const float4*)st + half * 64;
    float acc = 0.f;
    #pragma unroll 8
    for (int i = 0; i < 64; ++i) {
        float4 w = wr[i]; float4 x = sx[i];
        acc += w.x * x.x + w.y * x.y + w.z * x.z + w.w * x.w;
    }
    if (half) accs[hh] = acc;
    __syncthreads();
    if (!half) out[(size_t)b * H_ + h] = acc + accs[hh] + Whb[h];
}

extern "C" void kernel_launch(void* const* d_in, const int* in_sizes, int n_in,
                              void* d_out, int out_size, void* d_ws, size_t ws_size,
                              hipStream_t stream) {
    const float* sent_h  = (const float*)d_in[0];
    const float* rel     = (const float*)d_in[1];
    const float* pool    = (const float*)d_in[2];
    const int*   mask    = (const int*)d_in[3];
    const float* Wg_w    = (const float*)d_in[4];
    const float* Wg_b    = (const float*)d_in[5];
    const float* Wh_w    = (const float*)d_in[6];
    const float* Wh_b    = (const float*)d_in[7];
    const float* Wr_w    = (const float*)d_in[8];
    const float* Wr_b    = (const float*)d_in[9];
    const float* alpha_w = (const float*)d_in[10];
    const float* alpha_b = (const float*)d_in[11];
    float* out = (float*)d_out;

    char* ws = (char*)d_ws;
    u16*   whwb    = (u16*)ws;                       // 524288 B
    float* base    = (float*)(ws + 524288);          // 131072 B
    float* partial = (float*)(ws + 524288 + 131072); // 2097152 B
    float* tbuf    = (float*)(ws + 524288 + 131072 + 2097152); // 131072 B

    float* att_out = out;             // [64,512]
    float* w_out   = out + B_ * H_;   // [64,2048]

    k_base<<<dim3(256), dim3(256), 0, stream>>>(rel, pool, Wg_w, Wg_b, Wh_b, Wr_w, Wr_b, Wh_w, base, whwb);
    k_gemm<<<dim3((M_ / 128) * 4), dim3(256), 0, stream>>>(sent_h, whwb, base, alpha_w, partial);
    k_softmax<<<dim3(B_), dim3(256), 0, stream>>>(partial, mask, alpha_b, w_out);
    k_wsum<<<dim3(B_ * 8), dim3(256), 0, stream>>>(sent_h, w_out, tbuf);
    k_att<<<dim3(256), dim3(256), 0, stream>>>(tbuf, Wh_w, Wh_b, att_out);
}